// Round 9
// baseline (855.677 us; speedup 1.0000x reference)
//
#include <hip/hip_runtime.h>

#define SLEN 2048
#define DIM  64
#define NH   8
#define TQ   16
#define NEG_INF -1e9f

typedef __attribute__((ext_vector_type(8))) short short8;
typedef __attribute__((ext_vector_type(4))) float f32x4;
typedef unsigned short ushort;

__device__ inline ushort f2bf(float x) {
    unsigned u = __float_as_uint(x);
    u += 0x7fffu + ((u >> 16) & 1u);          // RNE (inputs finite)
    return (ushort)(u >> 16);
}
__device__ inline float bf2f(ushort b) {
    return __uint_as_float(((unsigned)b) << 16);
}

// ---- precompute 1: K -> bf16 hi/lo ----
__global__ __launch_bounds__(256)
void convk_kernel(const float* __restrict__ k,
                  ushort* __restrict__ khi, ushort* __restrict__ klo)
{
    int i4 = blockIdx.x * 256 + threadIdx.x;
    float4 x = ((const float4*)k)[i4];
    ushort h0 = f2bf(x.x), h1 = f2bf(x.y), h2 = f2bf(x.z), h3 = f2bf(x.w);
    ushort4 hi = {h0, h1, h2, h3};
    ushort4 lo = {f2bf(x.x - bf2f(h0)), f2bf(x.y - bf2f(h1)),
                  f2bf(x.z - bf2f(h2)), f2bf(x.w - bf2f(h3))};
    ((ushort4*)khi)[i4] = hi;
    ((ushort4*)klo)[i4] = lo;
}

// ---- precompute 2: V -> V^T bf16 ----
__global__ __launch_bounds__(256)
void convv_kernel(const float* __restrict__ v, ushort* __restrict__ vt)
{
    __shared__ ushort sT[64][70];
    const int h  = blockIdx.x >> 5;
    const int st = blockIdx.x & 31;
    const int t  = threadIdx.x;
    {
        const int r0 = t >> 4;
        const int c  = (t & 15) * 4;
        #pragma unroll
        for (int rr = r0; rr < 64; rr += 16) {
            float4 x = *(const float4*)(v + ((size_t)(h * SLEN + st * 64 + rr)) * DIM + c);
            sT[c + 0][rr] = f2bf(x.x);
            sT[c + 1][rr] = f2bf(x.y);
            sT[c + 2][rr] = f2bf(x.z);
            sT[c + 3][rr] = f2bf(x.w);
        }
    }
    __syncthreads();
    {
        const int d  = t >> 2;
        const int s0 = (t & 3) * 16;
        short8 a = *(const short8*)(&sT[d][s0]);
        short8 b = *(const short8*)(&sT[d][s0 + 8]);
        ushort* dst = vt + ((size_t)(h * DIM + d)) * SLEN + st * 64 + s0;
        *(short8*)(dst)     = a;
        *(short8*)(dst + 8) = b;
    }
}

// ---- precompute 3: mask int32 -> bitstring, 16 elems/thread ----
__global__ __launch_bounds__(256)
void convm_kernel(const int* __restrict__ mask, ushort* __restrict__ mb)
{
    size_t i = (size_t)blockIdx.x * 256 + threadIdx.x;
    const int4* p = (const int4*)(mask + i * 16);
    unsigned m = 0;
    #pragma unroll
    for (int w = 0; w < 4; ++w) {
        int4 a = p[w];
        m |= (a.x != 0 ? 1u : 0u) << (w * 4 + 0);
        m |= (a.y != 0 ? 1u : 0u) << (w * 4 + 1);
        m |= (a.z != 0 ? 1u : 0u) << (w * 4 + 2);
        m |= (a.w != 0 ? 1u : 0u) << (w * 4 + 3);
    }
    mb[i] = (ushort)m;
}

// ============================================================================
// ABLATION PROBES: R8 structure, one phase stubbed per MODE. They write
// garbage to p_out/out; the real kernel runs LAST and rewrites every output
// byte, so correctness is preserved while rocprof times each phase's cost.
//   MODE 1: no p_out stores   MODE 2: no sph stream   MODE 3: no QK^T
//   MODE 4: no softmax
// ============================================================================
template<int MODE>
__global__ __launch_bounds__(512, 2)
void attn_probe(const float* __restrict__ q,
                const ushort* __restrict__ khi,
                const ushort* __restrict__ klo,
                const ushort* __restrict__ vt,
                const float* __restrict__ sph,
                const unsigned* __restrict__ mbits,
                float* __restrict__ out,
                float* __restrict__ p_out)
{
    __shared__ ushort sP[TQ][SLEN + 8];
    __shared__ float  sS[TQ][1028];
    __shared__ ushort sQhi[TQ][72];
    __shared__ ushort sQlo[TQ][72];
    __shared__ float sMax[TQ][8];
    __shared__ float sSum[TQ][8];
    __shared__ float sC[4][TQ][16];

    const int tid  = threadIdx.x;
    const int wave = tid >> 6;
    const int lane = tid & 63;
    const int quad = lane >> 4;
    const int l16  = lane & 15;
    const int bx0  = blockIdx.x;
    const int bx   = ((bx0 & 7) << 7) | (bx0 >> 3);
    const int h    = bx >> 7;
    const int qr0  = (bx & 127) * TQ;

    {
        int e = tid * 2;
        int r = e >> 6, d = e & 63;
        float2 qv = *(const float2*)(q + ((size_t)(h * SLEN + qr0 + r)) * DIM + d);
        ushort h0 = f2bf(qv.x), h1 = f2bf(qv.y);
        sQhi[r][d]     = h0;
        sQhi[r][d + 1] = h1;
        sQlo[r][d]     = f2bf(qv.x - bf2f(h0));
        sQlo[r][d + 1] = f2bf(qv.y - bf2f(h1));
    }
    __syncthreads();

    short8 ah0 = *(const short8*)(&sQhi[l16][quad * 8]);
    short8 ah1 = *(const short8*)(&sQhi[l16][32 + quad * 8]);
    short8 al0 = *(const short8*)(&sQlo[l16][quad * 8]);
    short8 al1 = *(const short8*)(&sQlo[l16][32 + quad * 8]);

    const int cb0 = wave * 128;
    const int cb1 = 1024 + wave * 128;

    unsigned roA[4], roB[4];
    #pragma unroll
    for (int j = 0; j < 4; ++j) {
        unsigned rb = (unsigned)((h * SLEN + qr0 + quad * 4 + j) * SLEN);
        roA[j] = rb + cb0 + l16;
        roB[j] = rb + cb1 + l16;
    }

    unsigned mwA[4][4], mwB[4][4];
    #pragma unroll
    for (int j = 0; j < 4; ++j) {
        const unsigned* mr = mbits
            + (size_t)(h * SLEN + qr0 + quad * 4 + j) * (SLEN / 32);
        *(uint4*)mwA[j] = *(const uint4*)(mr + (cb0 >> 5));
        *(uint4*)mwB[j] = *(const uint4*)(mr + (cb1 >> 5));
    }

    const int srow = wave * 2;
    f32x4 g0[8];
    if constexpr (MODE != 2) {
        #pragma unroll
        for (int r = 0; r < 2; ++r)
            #pragma unroll
            for (int i = 0; i < 4; ++i)
                g0[r * 4 + i] = __builtin_nontemporal_load(
                    (const f32x4*)(sph + (size_t)(h * SLEN + qr0 + srow + r) * SLEN
                                       + i * 256 + lane * 4));
    }

    f32x4 c[16];
    #pragma unroll
    for (int t = 0; t < 16; ++t) c[t] = (f32x4){0.f, 0.f, 0.f, 0.f};

    if constexpr (MODE != 3) {
        #pragma unroll
        for (int t = 0; t < 16; ++t) {
            const int cb = (t < 8) ? (cb0 + t * 16) : (cb1 + (t - 8) * 16);
            const size_t rowb = ((size_t)(h * SLEN + cb + l16)) * DIM + quad * 8;
            short8 bh0 = *(const short8*)(khi + rowb);
            short8 bh1 = *(const short8*)(khi + rowb + 32);
            short8 bl0 = *(const short8*)(klo + rowb);
            short8 bl1 = *(const short8*)(klo + rowb + 32);
            c[t] = __builtin_amdgcn_mfma_f32_16x16x32_bf16(ah0, bh0, c[t], 0, 0, 0);
            c[t] = __builtin_amdgcn_mfma_f32_16x16x32_bf16(ah1, bh1, c[t], 0, 0, 0);
            c[t] = __builtin_amdgcn_mfma_f32_16x16x32_bf16(ah0, bl0, c[t], 0, 0, 0);
            c[t] = __builtin_amdgcn_mfma_f32_16x16x32_bf16(ah1, bl1, c[t], 0, 0, 0);
            c[t] = __builtin_amdgcn_mfma_f32_16x16x32_bf16(al0, bh0, c[t], 0, 0, 0);
            c[t] = __builtin_amdgcn_mfma_f32_16x16x32_bf16(al1, bh1, c[t], 0, 0, 0);
        }
    } else {
        // keep Q load alive (rule #17: ablation-via-skip DCEs upstream ops)
        int ka = ah0[0] ^ ah1[0] ^ al0[0] ^ al1[0];
        asm volatile("" :: "v"(ka));
    }

    if constexpr (MODE != 2) {
        #pragma unroll
        for (int r = 0; r < 2; ++r)
            #pragma unroll
            for (int i = 0; i < 4; ++i)
                *(f32x4*)&sS[srow + r][i * 256 + lane * 4] = g0[r * 4 + i];
        __syncthreads();
    }

    f32x4 g1[8];
    if constexpr (MODE != 2) {
        #pragma unroll
        for (int r = 0; r < 2; ++r)
            #pragma unroll
            for (int i = 0; i < 4; ++i)
                g1[r * 4 + i] = __builtin_nontemporal_load(
                    (const f32x4*)(sph + (size_t)(h * SLEN + qr0 + srow + r) * SLEN
                                       + 1024 + i * 256 + lane * 4));
    }

    float rmax[4] = {-3.4e38f, -3.4e38f, -3.4e38f, -3.4e38f};
    #pragma unroll
    for (int t = 0; t < 8; ++t) {
        #pragma unroll
        for (int j = 0; j < 4; ++j) {
            float sphv = (MODE == 2) ? 1.0f : sS[quad * 4 + j][cb0 + t * 16 + l16];
            float s = c[t][j] * 0.125f * sphv;
            const unsigned ok = (mwA[j][t >> 1] >> ((t & 1) * 16 + l16)) & 1u;
            s = ok ? s : NEG_INF;
            c[t][j] = s;
            rmax[j] = fmaxf(rmax[j], s);
        }
    }
    if constexpr (MODE != 2) {
        __syncthreads();
        #pragma unroll
        for (int r = 0; r < 2; ++r)
            #pragma unroll
            for (int i = 0; i < 4; ++i)
                *(f32x4*)&sS[srow + r][i * 256 + lane * 4] = g1[r * 4 + i];
        __syncthreads();
    }
    #pragma unroll
    for (int t = 8; t < 16; ++t) {
        #pragma unroll
        for (int j = 0; j < 4; ++j) {
            float sphv = (MODE == 2) ? 1.0f : sS[quad * 4 + j][cb0 + (t - 8) * 16 + l16];
            float s = c[t][j] * 0.125f * sphv;
            const unsigned ok =
                (mwB[j][(t - 8) >> 1] >> (((t - 8) & 1) * 16 + l16)) & 1u;
            s = ok ? s : NEG_INF;
            c[t][j] = s;
            rmax[j] = fmaxf(rmax[j], s);
        }
    }

    float inv[4] = {1.f, 1.f, 1.f, 1.f};
    if constexpr (MODE != 4) {
        #pragma unroll
        for (int off = 1; off <= 8; off <<= 1) {
            #pragma unroll
            for (int j = 0; j < 4; ++j)
                rmax[j] = fmaxf(rmax[j], __shfl_xor(rmax[j], off));
        }
        if (l16 == 0) {
            #pragma unroll
            for (int j = 0; j < 4; ++j) sMax[quad * 4 + j][wave] = rmax[j];
        }
        __syncthreads();
        float M[4];
        #pragma unroll
        for (int j = 0; j < 4; ++j) {
            float m = sMax[quad * 4 + j][0];
            #pragma unroll
            for (int w = 1; w < 8; ++w) m = fmaxf(m, sMax[quad * 4 + j][w]);
            M[j] = m;
        }
        float rsum[4] = {0.f, 0.f, 0.f, 0.f};
        #pragma unroll
        for (int t = 0; t < 16; ++t) {
            #pragma unroll
            for (int j = 0; j < 4; ++j) {
                float e = __expf(c[t][j] - M[j]);
                c[t][j] = e;
                rsum[j] += e;
            }
        }
        #pragma unroll
        for (int off = 1; off <= 8; off <<= 1) {
            #pragma unroll
            for (int j = 0; j < 4; ++j)
                rsum[j] += __shfl_xor(rsum[j], off);
        }
        if (l16 == 0) {
            #pragma unroll
            for (int j = 0; j < 4; ++j) sSum[quad * 4 + j][wave] = rsum[j];
        }
        __syncthreads();
        #pragma unroll
        for (int j = 0; j < 4; ++j) {
            float s = 0.f;
            #pragma unroll
            for (int w = 0; w < 8; ++w) s += sSum[quad * 4 + j][w];
            inv[j] = 1.0f / s;
        }
    }

    #pragma unroll
    for (int t = 0; t < 16; ++t) {
        #pragma unroll
        for (int j = 0; j < 4; ++j) {
            const int col = ((t < 8) ? (cb0 + t * 16) : (cb1 + (t - 8) * 16)) + l16;
            float p = c[t][j] * inv[j];
            c[t][j] = p;
            sP[quad * 4 + j][col] = f2bf(p);
        }
    }
    __syncthreads();

    if constexpr (MODE != 1) {
        #pragma unroll
        for (int t = 0; t < 16; ++t) {
            #pragma unroll
            for (int j = 0; j < 4; ++j)
                p_out[(t < 8) ? (roA[j] + t * 16) : (roB[j] + (t - 8) * 16)] = c[t][j];
        }
    }

    const int ntile = wave & 3;
    const int khalf = wave >> 2;
    f32x4 o = (f32x4){0.f, 0.f, 0.f, 0.f};
    const ushort* vb = vt + ((size_t)(h * DIM + ntile * 16 + l16)) * SLEN
                          + khalf * 1024 + quad * 8;
    #pragma unroll 8
    for (int s = 0; s < 32; ++s) {
        short8 a = *(const short8*)(&sP[l16][khalf * 1024 + s * 32 + quad * 8]);
        short8 b = *(const short8*)(vb + s * 32);
        o = __builtin_amdgcn_mfma_f32_16x16x32_bf16(a, b, o, 0, 0, 0);
    }
    if (wave >= 4) {
        #pragma unroll
        for (int j = 0; j < 4; ++j) sC[ntile][quad * 4 + j][l16] = o[j];
    }
    __syncthreads();
    if (wave < 4) {
        #pragma unroll
        for (int j = 0; j < 4; ++j) {
            float r = o[j] + sC[ntile][quad * 4 + j][l16];
            out[((size_t)(h * SLEN) + qr0 + quad * 4 + j) * DIM + ntile * 16 + l16] = r;
        }
    }
}

// ============================================================================
// REAL kernel (runs LAST): R8 + coalesced p_out stores. p (full f32) is
// restaged through sS (free after consumption) and written as f32x4/lane
// full-line stores (1 KB/instr) in two 64 KB halves -- replaces 64 scattered
// 4B-per-lane stores (4x64-B segments/instr) per lane.
// ============================================================================
__global__ __launch_bounds__(512, 2)
void attn_mfma_kernel(const float* __restrict__ q,
                      const ushort* __restrict__ khi,
                      const ushort* __restrict__ klo,
                      const ushort* __restrict__ vt,
                      const float* __restrict__ sph,
                      const unsigned* __restrict__ mbits,
                      float* __restrict__ out,
                      float* __restrict__ p_out)
{
    __shared__ ushort sP[TQ][SLEN + 8];
    __shared__ float  sS[TQ][1028];   // stride 1028: dRow4 -> dBank16 -> 2-way (free)
    __shared__ ushort sQhi[TQ][72];
    __shared__ ushort sQlo[TQ][72];
    __shared__ float sMax[TQ][8];
    __shared__ float sSum[TQ][8];
    __shared__ float sC[4][TQ][16];

    const int tid  = threadIdx.x;
    const int wave = tid >> 6;
    const int lane = tid & 63;
    const int quad = lane >> 4;
    const int l16  = lane & 15;
    const int bx0  = blockIdx.x;
    const int bx   = ((bx0 & 7) << 7) | (bx0 >> 3);
    const int h    = bx >> 7;
    const int qr0  = (bx & 127) * TQ;

    {
        int e = tid * 2;
        int r = e >> 6, d = e & 63;
        float2 qv = *(const float2*)(q + ((size_t)(h * SLEN + qr0 + r)) * DIM + d);
        ushort h0 = f2bf(qv.x), h1 = f2bf(qv.y);
        sQhi[r][d]     = h0;
        sQhi[r][d + 1] = h1;
        sQlo[r][d]     = f2bf(qv.x - bf2f(h0));
        sQlo[r][d + 1] = f2bf(qv.y - bf2f(h1));
    }
    __syncthreads();

    short8 ah0 = *(const short8*)(&sQhi[l16][quad * 8]);
    short8 ah1 = *(const short8*)(&sQhi[l16][32 + quad * 8]);
    short8 al0 = *(const short8*)(&sQlo[l16][quad * 8]);
    short8 al1 = *(const short8*)(&sQlo[l16][32 + quad * 8]);

    const int cb0 = wave * 128;
    const int cb1 = 1024 + wave * 128;

    unsigned mwA[4][4], mwB[4][4];
    #pragma unroll
    for (int j = 0; j < 4; ++j) {
        const unsigned* mr = mbits
            + (size_t)(h * SLEN + qr0 + quad * 4 + j) * (SLEN / 32);
        *(uint4*)mwA[j] = *(const uint4*)(mr + (cb0 >> 5));
        *(uint4*)mwB[j] = *(const uint4*)(mr + (cb1 >> 5));
    }

    const int srow = wave * 2;
    f32x4 g0[8];
    #pragma unroll
    for (int r = 0; r < 2; ++r)
        #pragma unroll
        for (int i = 0; i < 4; ++i)
            g0[r * 4 + i] = __builtin_nontemporal_load(
                (const f32x4*)(sph + (size_t)(h * SLEN + qr0 + srow + r) * SLEN
                                   + i * 256 + lane * 4));

    f32x4 c[16];
    #pragma unroll
    for (int t = 0; t < 16; ++t) c[t] = (f32x4){0.f, 0.f, 0.f, 0.f};

    #pragma unroll
    for (int t = 0; t < 16; ++t) {
        const int cb = (t < 8) ? (cb0 + t * 16) : (cb1 + (t - 8) * 16);
        const size_t rowb = ((size_t)(h * SLEN + cb + l16)) * DIM + quad * 8;
        short8 bh0 = *(const short8*)(khi + rowb);
        short8 bh1 = *(const short8*)(khi + rowb + 32);
        short8 bl0 = *(const short8*)(klo + rowb);
        short8 bl1 = *(const short8*)(klo + rowb + 32);
        c[t] = __builtin_amdgcn_mfma_f32_16x16x32_bf16(ah0, bh0, c[t], 0, 0, 0);
        c[t] = __builtin_amdgcn_mfma_f32_16x16x32_bf16(ah1, bh1, c[t], 0, 0, 0);
        c[t] = __builtin_amdgcn_mfma_f32_16x16x32_bf16(ah0, bl0, c[t], 0, 0, 0);
        c[t] = __builtin_amdgcn_mfma_f32_16x16x32_bf16(ah1, bl1, c[t], 0, 0, 0);
        c[t] = __builtin_amdgcn_mfma_f32_16x16x32_bf16(al0, bh0, c[t], 0, 0, 0);
        c[t] = __builtin_amdgcn_mfma_f32_16x16x32_bf16(al1, bh1, c[t], 0, 0, 0);
    }

    #pragma unroll
    for (int r = 0; r < 2; ++r)
        #pragma unroll
        for (int i = 0; i < 4; ++i)
            *(f32x4*)&sS[srow + r][i * 256 + lane * 4] = g0[r * 4 + i];
    __syncthreads();

    f32x4 g1[8];
    #pragma unroll
    for (int r = 0; r < 2; ++r)
        #pragma unroll
        for (int i = 0; i < 4; ++i)
            g1[r * 4 + i] = __builtin_nontemporal_load(
                (const f32x4*)(sph + (size_t)(h * SLEN + qr0 + srow + r) * SLEN
                                   + 1024 + i * 256 + lane * 4));

    float rmax[4] = {-3.4e38f, -3.4e38f, -3.4e38f, -3.4e38f};
    #pragma unroll
    for (int t = 0; t < 8; ++t) {
        #pragma unroll
        for (int j = 0; j < 4; ++j) {
            float sphv = sS[quad * 4 + j][cb0 + t * 16 + l16];
            float s = c[t][j] * 0.125f * sphv;
            const unsigned ok = (mwA[j][t >> 1] >> ((t & 1) * 16 + l16)) & 1u;
            s = ok ? s : NEG_INF;
            c[t][j] = s;
            rmax[j] = fmaxf(rmax[j], s);
        }
    }
    __syncthreads();

    #pragma unroll
    for (int r = 0; r < 2; ++r)
        #pragma unroll
        for (int i = 0; i < 4; ++i)
            *(f32x4*)&sS[srow + r][i * 256 + lane * 4] = g1[r * 4 + i];
    __syncthreads();

    #pragma unroll
    for (int t = 8; t < 16; ++t) {
        #pragma unroll
        for (int j = 0; j < 4; ++j) {
            float sphv = sS[quad * 4 + j][cb0 + (t - 8) * 16 + l16];
            float s = c[t][j] * 0.125f * sphv;
            const unsigned ok =
                (mwB[j][(t - 8) >> 1] >> (((t - 8) & 1) * 16 + l16)) & 1u;
            s = ok ? s : NEG_INF;
            c[t][j] = s;
            rmax[j] = fmaxf(rmax[j], s);
        }
    }

    #pragma unroll
    for (int off = 1; off <= 8; off <<= 1) {
        #pragma unroll
        for (int j = 0; j < 4; ++j)
            rmax[j] = fmaxf(rmax[j], __shfl_xor(rmax[j], off));
    }
    if (l16 == 0) {
        #pragma unroll
        for (int j = 0; j < 4; ++j) sMax[quad * 4 + j][wave] = rmax[j];
    }
    __syncthreads();

    float M[4];
    #pragma unroll
    for (int j = 0; j < 4; ++j) {
        float m = sMax[quad * 4 + j][0];
        #pragma unroll
        for (int w = 1; w < 8; ++w) m = fmaxf(m, sMax[quad * 4 + j][w]);
        M[j] = m;
    }

    float rsum[4] = {0.f, 0.f, 0.f, 0.f};
    #pragma unroll
    for (int t = 0; t < 16; ++t) {
        #pragma unroll
        for (int j = 0; j < 4; ++j) {
            float e = __expf(c[t][j] - M[j]);
            c[t][j] = e;
            rsum[j] += e;
        }
    }
    #pragma unroll
    for (int off = 1; off <= 8; off <<= 1) {
        #pragma unroll
        for (int j = 0; j < 4; ++j)
            rsum[j] += __shfl_xor(rsum[j], off);
    }
    if (l16 == 0) {
        #pragma unroll
        for (int j = 0; j < 4; ++j) sSum[quad * 4 + j][wave] = rsum[j];
    }
    __syncthreads();

    float inv[4];
    #pragma unroll
    for (int j = 0; j < 4; ++j) {
        float s = 0.f;
        #pragma unroll
        for (int w = 0; w < 8; ++w) s += sSum[quad * 4 + j][w];
        inv[j] = 1.0f / s;
    }

    // ---- normalize: p (f32) into c[], bf16 into sP ----
    #pragma unroll
    for (int t = 0; t < 16; ++t) {
        #pragma unroll
        for (int j = 0; j < 4; ++j) {
            const int col = ((t < 8) ? (cb0 + t * 16) : (cb1 + (t - 8) * 16)) + l16;
            float p = c[t][j] * inv[j];
            c[t][j] = p;
            sP[quad * 4 + j][col] = f2bf(p);
        }
    }

    // ---- coalesced p_out: scatter p into sS, read back row-contiguous,
    // store f32x4/lane full lines. Two 64 KB halves. ----
    #pragma unroll
    for (int t = 0; t < 8; ++t) {
        #pragma unroll
        for (int j = 0; j < 4; ++j)
            sS[quad * 4 + j][cb0 + t * 16 + l16] = c[t][j];
    }
    __syncthreads();
    #pragma unroll
    for (int r = 0; r < 2; ++r) {
        #pragma unroll
        for (int i = 0; i < 4; ++i) {
            f32x4 v = *(const f32x4*)&sS[srow + r][i * 256 + lane * 4];
            *(f32x4*)(p_out + (size_t)(h * SLEN + qr0 + srow + r) * SLEN
                            + i * 256 + lane * 4) = v;
        }
    }
    __syncthreads();
    #pragma unroll
    for (int t = 8; t < 16; ++t) {
        #pragma unroll
        for (int j = 0; j < 4; ++j)
            sS[quad * 4 + j][cb0 + (t - 8) * 16 + l16] = c[t][j];
    }
    __syncthreads();
    #pragma unroll
    for (int r = 0; r < 2; ++r) {
        #pragma unroll
        for (int i = 0; i < 4; ++i) {
            f32x4 v = *(const f32x4*)&sS[srow + r][i * 256 + lane * 4];
            *(f32x4*)(p_out + (size_t)(h * SLEN + qr0 + srow + r) * SLEN
                            + 1024 + i * 256 + lane * 4) = v;
        }
    }
    __syncthreads();   // also guards sP for PV (written long before)

    // ---- PV ----
    const int ntile = wave & 3;
    const int khalf = wave >> 2;
    f32x4 o = (f32x4){0.f, 0.f, 0.f, 0.f};
    const ushort* vb = vt + ((size_t)(h * DIM + ntile * 16 + l16)) * SLEN
                          + khalf * 1024 + quad * 8;
    #pragma unroll 8
    for (int s = 0; s < 32; ++s) {
        short8 a = *(const short8*)(&sP[l16][khalf * 1024 + s * 32 + quad * 8]);
        short8 b = *(const short8*)(vb + s * 32);
        o = __builtin_amdgcn_mfma_f32_16x16x32_bf16(a, b, o, 0, 0, 0);
    }
    if (wave >= 4) {
        #pragma unroll
        for (int j = 0; j < 4; ++j) sC[ntile][quad * 4 + j][l16] = o[j];
    }
    __syncthreads();
    if (wave < 4) {
        #pragma unroll
        for (int j = 0; j < 4; ++j) {
            float r = o[j] + sC[ntile][quad * 4 + j][l16];
            out[((size_t)(h * SLEN) + qr0 + quad * 4 + j) * DIM + ntile * 16 + l16] = r;
        }
    }
}

extern "C" void kernel_launch(void* const* d_in, const int* in_sizes, int n_in,
                              void* d_out, int out_size, void* d_ws, size_t ws_size,
                              hipStream_t stream) {
    const float* q    = (const float*)d_in[0];
    const float* k    = (const float*)d_in[1];
    const float* v    = (const float*)d_in[2];
    const float* sph  = (const float*)d_in[3];
    const int*   mask = (const int*)d_in[4];
    float* out   = (float*)d_out;
    float* p_out = out + (size_t)NH * SLEN * DIM;

    const size_t nkv = (size_t)NH * SLEN * DIM;
    ushort* khi = (ushort*)d_ws;
    ushort* klo = khi + nkv;
    ushort* vt  = klo + nkv;
    ushort* mbits = vt + nkv;

    const size_t nmask = (size_t)NH * SLEN * SLEN;

    hipLaunchKernelGGL(convk_kernel, dim3(nkv / 4 / 256), dim3(256), 0, stream,
                       k, khi, klo);
    hipLaunchKernelGGL(convv_kernel, dim3(NH * (SLEN / 64)), dim3(256), 0, stream,
                       v, vt);
    hipLaunchKernelGGL(convm_kernel, dim3(nmask / 16 / 256), dim3(256), 0, stream,
                       mask, mbits);

    // ---- ablation probes (garbage outputs; real kernel rewrites all) ----
    dim3 g(NH * (SLEN / TQ)), b(512);
    hipLaunchKernelGGL(attn_probe<1>, g, b, 0, stream, q, khi, klo, vt, sph,
                       (const unsigned*)mbits, out, p_out);   // no p_out stores
    hipLaunchKernelGGL(attn_probe<2>, g, b, 0, stream, q, khi, klo, vt, sph,
                       (const unsigned*)mbits, out, p_out);   // no sph stream
    hipLaunchKernelGGL(attn_probe<3>, g, b, 0, stream, q, khi, klo, vt, sph,
                       (const unsigned*)mbits, out, p_out);   // no QK^T
    hipLaunchKernelGGL(attn_probe<4>, g, b, 0, stream, q, khi, klo, vt, sph,
                       (const unsigned*)mbits, out, p_out);   // no softmax

    // ---- real kernel LAST: overwrites every output byte ----
    hipLaunchKernelGGL(attn_mfma_kernel, g, b, 0, stream,
                       q, khi, klo, vt, sph, (const unsigned*)mbits, out, p_out);
}

// Round 10
// 420.791 us; speedup vs baseline: 2.0335x; 2.0335x over previous
//
#include <hip/hip_runtime.h>

#define SLEN 2048
#define DIM  64
#define NH   8
#define TQ   16
#define NEG_INF -1e9f

typedef __attribute__((ext_vector_type(8))) short short8;
typedef __attribute__((ext_vector_type(4))) float f32x4;
typedef unsigned short ushort;

__device__ inline ushort f2bf(float x) {
    unsigned u = __float_as_uint(x);
    u += 0x7fffu + ((u >> 16) & 1u);          // RNE (inputs finite)
    return (ushort)(u >> 16);
}
__device__ inline float bf2f(ushort b) {
    return __uint_as_float(((unsigned)b) << 16);
}

// Raw workgroup barrier WITHOUT the compiler's vmcnt(0) drain.
// __syncthreads makes hipcc emit `s_waitcnt vmcnt(0) lgkmcnt(0)` before
// s_barrier -- forcing ALL in-flight global loads/stores to retire at every
// phase boundary (~10 barriers/block x 4 blocks/CU = the round-0..9
// invariant ~140us). lgkmcnt(0) keeps LDS produce->consume correct; register
// data deps on global loads still get compiler-inserted COUNTED vmcnt waits
// at the use site, so loads/stores stay in flight across phases.
__device__ inline void xbar() {
    asm volatile("s_waitcnt lgkmcnt(0)\n\ts_barrier" ::: "memory");
}

// ---- precompute 1: K -> bf16 hi/lo ----
__global__ __launch_bounds__(256)
void convk_kernel(const float* __restrict__ k,
                  ushort* __restrict__ khi, ushort* __restrict__ klo)
{
    int i4 = blockIdx.x * 256 + threadIdx.x;
    float4 x = ((const float4*)k)[i4];
    ushort h0 = f2bf(x.x), h1 = f2bf(x.y), h2 = f2bf(x.z), h3 = f2bf(x.w);
    ushort4 hi = {h0, h1, h2, h3};
    ushort4 lo = {f2bf(x.x - bf2f(h0)), f2bf(x.y - bf2f(h1)),
                  f2bf(x.z - bf2f(h2)), f2bf(x.w - bf2f(h3))};
    ((ushort4*)khi)[i4] = hi;
    ((ushort4*)klo)[i4] = lo;
}

// ---- precompute 2: V -> V^T bf16 ----
__global__ __launch_bounds__(256)
void convv_kernel(const float* __restrict__ v, ushort* __restrict__ vt)
{
    __shared__ ushort sT[64][70];
    const int h  = blockIdx.x >> 5;
    const int st = blockIdx.x & 31;
    const int t  = threadIdx.x;
    {
        const int r0 = t >> 4;
        const int c  = (t & 15) * 4;
        #pragma unroll
        for (int rr = r0; rr < 64; rr += 16) {
            float4 x = *(const float4*)(v + ((size_t)(h * SLEN + st * 64 + rr)) * DIM + c);
            sT[c + 0][rr] = f2bf(x.x);
            sT[c + 1][rr] = f2bf(x.y);
            sT[c + 2][rr] = f2bf(x.z);
            sT[c + 3][rr] = f2bf(x.w);
        }
    }
    __syncthreads();
    {
        const int d  = t >> 2;
        const int s0 = (t & 3) * 16;
        short8 a = *(const short8*)(&sT[d][s0]);
        short8 b = *(const short8*)(&sT[d][s0 + 8]);
        ushort* dst = vt + ((size_t)(h * DIM + d)) * SLEN + st * 64 + s0;
        *(short8*)(dst)     = a;
        *(short8*)(dst + 8) = b;
    }
}

// ---- precompute 3: mask int32 -> bitstring, 16 elems/thread ----
__global__ __launch_bounds__(256)
void convm_kernel(const int* __restrict__ mask, ushort* __restrict__ mb)
{
    size_t i = (size_t)blockIdx.x * 256 + threadIdx.x;
    const int4* p = (const int4*)(mask + i * 16);
    unsigned m = 0;
    #pragma unroll
    for (int w = 0; w < 4; ++w) {
        int4 a = p[w];
        m |= (a.x != 0 ? 1u : 0u) << (w * 4 + 0);
        m |= (a.y != 0 ? 1u : 0u) << (w * 4 + 1);
        m |= (a.z != 0 ? 1u : 0u) << (w * 4 + 2);
        m |= (a.w != 0 ? 1u : 0u) << (w * 4 + 3);
    }
    mb[i] = (ushort)m;
}

// ---- main: R9 structure + no-drain barriers + stores-after-PV ----
__global__ __launch_bounds__(512, 2)
void attn_mfma_kernel(const float* __restrict__ q,
                      const ushort* __restrict__ khi,
                      const ushort* __restrict__ klo,
                      const ushort* __restrict__ vt,
                      const float* __restrict__ sph,
                      const unsigned* __restrict__ mbits,
                      float* __restrict__ out,
                      float* __restrict__ p_out)
{
    __shared__ ushort sP[TQ][SLEN + 8];
    __shared__ float  sS[TQ][1028];
    __shared__ ushort sQhi[TQ][72];
    __shared__ ushort sQlo[TQ][72];
    __shared__ float sMax[TQ][8];
    __shared__ float sSum[TQ][8];
    __shared__ float sC[4][TQ][16];

    const int tid  = threadIdx.x;
    const int wave = tid >> 6;
    const int lane = tid & 63;
    const int quad = lane >> 4;
    const int l16  = lane & 15;
    const int bx0  = blockIdx.x;
    const int bx   = ((bx0 & 7) << 7) | (bx0 >> 3);
    const int h    = bx >> 7;
    const int qr0  = (bx & 127) * TQ;

    {
        int e = tid * 2;
        int r = e >> 6, d = e & 63;
        float2 qv = *(const float2*)(q + ((size_t)(h * SLEN + qr0 + r)) * DIM + d);
        ushort h0 = f2bf(qv.x), h1 = f2bf(qv.y);
        sQhi[r][d]     = h0;
        sQhi[r][d + 1] = h1;
        sQlo[r][d]     = f2bf(qv.x - bf2f(h0));
        sQlo[r][d + 1] = f2bf(qv.y - bf2f(h1));
    }
    xbar();

    short8 ah0 = *(const short8*)(&sQhi[l16][quad * 8]);
    short8 ah1 = *(const short8*)(&sQhi[l16][32 + quad * 8]);
    short8 al0 = *(const short8*)(&sQlo[l16][quad * 8]);
    short8 al1 = *(const short8*)(&sQlo[l16][32 + quad * 8]);

    const int cb0 = wave * 128;
    const int cb1 = 1024 + wave * 128;

    unsigned mwA[4][4], mwB[4][4];
    #pragma unroll
    for (int j = 0; j < 4; ++j) {
        const unsigned* mr = mbits
            + (size_t)(h * SLEN + qr0 + quad * 4 + j) * (SLEN / 32);
        *(uint4*)mwA[j] = *(const uint4*)(mr + (cb0 >> 5));
        *(uint4*)mwB[j] = *(const uint4*)(mr + (cb1 >> 5));
    }

    // issue half-0 sph loads; they fly under QK^T (and now genuinely stay
    // in flight across barriers)
    const int srow = wave * 2;
    f32x4 g0[8];
    #pragma unroll
    for (int r = 0; r < 2; ++r)
        #pragma unroll
        for (int i = 0; i < 4; ++i)
            g0[r * 4 + i] = __builtin_nontemporal_load(
                (const f32x4*)(sph + (size_t)(h * SLEN + qr0 + srow + r) * SLEN
                                   + i * 256 + lane * 4));

    f32x4 c[16];
    #pragma unroll
    for (int t = 0; t < 16; ++t) c[t] = (f32x4){0.f, 0.f, 0.f, 0.f};

    #pragma unroll
    for (int t = 0; t < 16; ++t) {
        const int cb = (t < 8) ? (cb0 + t * 16) : (cb1 + (t - 8) * 16);
        const size_t rowb = ((size_t)(h * SLEN + cb + l16)) * DIM + quad * 8;
        short8 bh0 = *(const short8*)(khi + rowb);
        short8 bh1 = *(const short8*)(khi + rowb + 32);
        short8 bl0 = *(const short8*)(klo + rowb);
        short8 bl1 = *(const short8*)(klo + rowb + 32);
        c[t] = __builtin_amdgcn_mfma_f32_16x16x32_bf16(ah0, bh0, c[t], 0, 0, 0);
        c[t] = __builtin_amdgcn_mfma_f32_16x16x32_bf16(ah1, bh1, c[t], 0, 0, 0);
        c[t] = __builtin_amdgcn_mfma_f32_16x16x32_bf16(ah0, bl0, c[t], 0, 0, 0);
        c[t] = __builtin_amdgcn_mfma_f32_16x16x32_bf16(ah1, bl1, c[t], 0, 0, 0);
        c[t] = __builtin_amdgcn_mfma_f32_16x16x32_bf16(al0, bh0, c[t], 0, 0, 0);
        c[t] = __builtin_amdgcn_mfma_f32_16x16x32_bf16(al1, bh1, c[t], 0, 0, 0);
    }

    // commit half-0 (counted vmcnt wait on g0 only -- K loads may still fly)
    #pragma unroll
    for (int r = 0; r < 2; ++r)
        #pragma unroll
        for (int i = 0; i < 4; ++i)
            *(f32x4*)&sS[srow + r][i * 256 + lane * 4] = g0[r * 4 + i];
    xbar();

    // issue half-1; with xbar it truly stays in flight under half-0 consume
    f32x4 g1[8];
    #pragma unroll
    for (int r = 0; r < 2; ++r)
        #pragma unroll
        for (int i = 0; i < 4; ++i)
            g1[r * 4 + i] = __builtin_nontemporal_load(
                (const f32x4*)(sph + (size_t)(h * SLEN + qr0 + srow + r) * SLEN
                                   + 1024 + i * 256 + lane * 4));

    float rmax[4] = {-3.4e38f, -3.4e38f, -3.4e38f, -3.4e38f};
    #pragma unroll
    for (int t = 0; t < 8; ++t) {
        #pragma unroll
        for (int j = 0; j < 4; ++j) {
            float sphv = sS[quad * 4 + j][cb0 + t * 16 + l16];
            float s = c[t][j] * 0.125f * sphv;
            const unsigned ok = (mwA[j][t >> 1] >> ((t & 1) * 16 + l16)) & 1u;
            s = ok ? s : NEG_INF;
            c[t][j] = s;
            rmax[j] = fmaxf(rmax[j], s);
        }
    }
    xbar();   // lgkmcnt(0): all half-0 ds_reads complete before overwrite

    #pragma unroll
    for (int r = 0; r < 2; ++r)
        #pragma unroll
        for (int i = 0; i < 4; ++i)
            *(f32x4*)&sS[srow + r][i * 256 + lane * 4] = g1[r * 4 + i];
    xbar();

    #pragma unroll
    for (int t = 8; t < 16; ++t) {
        #pragma unroll
        for (int j = 0; j < 4; ++j) {
            float sphv = sS[quad * 4 + j][cb0 + (t - 8) * 16 + l16];
            float s = c[t][j] * 0.125f * sphv;
            const unsigned ok =
                (mwB[j][(t - 8) >> 1] >> (((t - 8) & 1) * 16 + l16)) & 1u;
            s = ok ? s : NEG_INF;
            c[t][j] = s;
            rmax[j] = fmaxf(rmax[j], s);
        }
    }

    #pragma unroll
    for (int off = 1; off <= 8; off <<= 1) {
        #pragma unroll
        for (int j = 0; j < 4; ++j)
            rmax[j] = fmaxf(rmax[j], __shfl_xor(rmax[j], off));
    }
    if (l16 == 0) {
        #pragma unroll
        for (int j = 0; j < 4; ++j) sMax[quad * 4 + j][wave] = rmax[j];
    }
    xbar();

    float M[4];
    #pragma unroll
    for (int j = 0; j < 4; ++j) {
        float m = sMax[quad * 4 + j][0];
        #pragma unroll
        for (int w = 1; w < 8; ++w) m = fmaxf(m, sMax[quad * 4 + j][w]);
        M[j] = m;
    }

    float rsum[4] = {0.f, 0.f, 0.f, 0.f};
    #pragma unroll
    for (int t = 0; t < 16; ++t) {
        #pragma unroll
        for (int j = 0; j < 4; ++j) {
            float e = __expf(c[t][j] - M[j]);
            c[t][j] = e;
            rsum[j] += e;
        }
    }
    #pragma unroll
    for (int off = 1; off <= 8; off <<= 1) {
        #pragma unroll
        for (int j = 0; j < 4; ++j)
            rsum[j] += __shfl_xor(rsum[j], off);
    }
    if (l16 == 0) {
        #pragma unroll
        for (int j = 0; j < 4; ++j) sSum[quad * 4 + j][wave] = rsum[j];
    }
    xbar();

    float inv[4];
    #pragma unroll
    for (int j = 0; j < 4; ++j) {
        float s = 0.f;
        #pragma unroll
        for (int w = 0; w < 8; ++w) s += sSum[quad * 4 + j][w];
        inv[j] = 1.0f / s;
    }

    // normalize: p (f32) kept in c[], bf16 into sP for PV
    #pragma unroll
    for (int t = 0; t < 16; ++t) {
        #pragma unroll
        for (int j = 0; j < 4; ++j) {
            const int col = ((t < 8) ? (cb0 + t * 16) : (cb1 + (t - 8) * 16)) + l16;
            float p = c[t][j] * inv[j];
            c[t][j] = p;
            sP[quad * 4 + j][col] = f2bf(p);
        }
    }
    xbar();

    // ---- PV FIRST (its V-loads must precede p_out stores: vmcnt is FIFO,
    // so a V-load wait would otherwise force all older stores to retire) ----
    const int ntile = wave & 3;
    const int khalf = wave >> 2;
    f32x4 o = (f32x4){0.f, 0.f, 0.f, 0.f};
    const ushort* vb = vt + ((size_t)(h * DIM + ntile * 16 + l16)) * SLEN
                          + khalf * 1024 + quad * 8;
    #pragma unroll 8
    for (int s = 0; s < 32; ++s) {
        short8 a = *(const short8*)(&sP[l16][khalf * 1024 + s * 32 + quad * 8]);
        short8 b = *(const short8*)(vb + s * 32);
        o = __builtin_amdgcn_mfma_f32_16x16x32_bf16(a, b, o, 0, 0, 0);
    }
    if (wave >= 4) {
        #pragma unroll
        for (int j = 0; j < 4; ++j) sC[ntile][quad * 4 + j][l16] = o[j];
    }
    xbar();
    float orow[4] = {0.f, 0.f, 0.f, 0.f};
    if (wave < 4) {
        #pragma unroll
        for (int j = 0; j < 4; ++j)
            orow[j] = o[j] + sC[ntile][quad * 4 + j][l16];
    }

    // ---- p_out stores LAST: restage p through sS (free), store f32x4 full
    // lines; nothing downstream waits on them (drain overlaps next block) ----
    #pragma unroll
    for (int t = 0; t < 8; ++t) {
        #pragma unroll
        for (int j = 0; j < 4; ++j)
            sS[quad * 4 + j][cb0 + t * 16 + l16] = c[t][j];
    }
    xbar();
    #pragma unroll
    for (int r = 0; r < 2; ++r) {
        #pragma unroll
        for (int i = 0; i < 4; ++i) {
            f32x4 v = *(const f32x4*)&sS[srow + r][i * 256 + lane * 4];
            *(f32x4*)(p_out + (size_t)(h * SLEN + qr0 + srow + r) * SLEN
                            + i * 256 + lane * 4) = v;
        }
    }
    xbar();
    #pragma unroll
    for (int t = 8; t < 16; ++t) {
        #pragma unroll
        for (int j = 0; j < 4; ++j)
            sS[quad * 4 + j][cb0 + (t - 8) * 16 + l16] = c[t][j];
    }
    xbar();
    #pragma unroll
    for (int r = 0; r < 2; ++r) {
        #pragma unroll
        for (int i = 0; i < 4; ++i) {
            f32x4 v = *(const f32x4*)&sS[srow + r][i * 256 + lane * 4];
            *(f32x4*)(p_out + (size_t)(h * SLEN + qr0 + srow + r) * SLEN
                            + 1024 + i * 256 + lane * 4) = v;
        }
    }

    if (wave < 4) {
        #pragma unroll
        for (int j = 0; j < 4; ++j)
            out[((size_t)(h * SLEN) + qr0 + quad * 4 + j) * DIM + ntile * 16 + l16]
                = orow[j];
    }
}

extern "C" void kernel_launch(void* const* d_in, const int* in_sizes, int n_in,
                              void* d_out, int out_size, void* d_ws, size_t ws_size,
                              hipStream_t stream) {
    const float* q    = (const float*)d_in[0];
    const float* k    = (const float*)d_in[1];
    const float* v    = (const float*)d_in[2];
    const float* sph  = (const float*)d_in[3];
    const int*   mask = (const int*)d_in[4];
    float* out   = (float*)d_out;
    float* p_out = out + (size_t)NH * SLEN * DIM;

    const size_t nkv = (size_t)NH * SLEN * DIM;
    ushort* khi = (ushort*)d_ws;
    ushort* klo = khi + nkv;
    ushort* vt  = klo + nkv;
    ushort* mbits = vt + nkv;

    const size_t nmask = (size_t)NH * SLEN * SLEN;

    hipLaunchKernelGGL(convk_kernel, dim3(nkv / 4 / 256), dim3(256), 0, stream,
                       k, khi, klo);
    hipLaunchKernelGGL(convv_kernel, dim3(NH * (SLEN / 64)), dim3(256), 0, stream,
                       v, vt);
    hipLaunchKernelGGL(convm_kernel, dim3(nmask / 16 / 256), dim3(256), 0, stream,
                       mask, mbits);
    hipLaunchKernelGGL(attn_mfma_kernel, dim3(NH * (SLEN / TQ)), dim3(512), 0, stream,
                       q, khi, klo, vt, sph, (const unsigned*)mbits, out, p_out);
}